// Round 8
// baseline (550.940 us; speedup 1.0000x reference)
//
#include <hip/hip_runtime.h>
#include <math.h>

#define S 512
#define B 128
#define T 256
#define NTH 256
#define LOG2E 1.44269504f
#define LN2 0.69314718f

typedef _Float16 h2 __attribute__((ext_vector_type(2)));
typedef _Float16 h8 __attribute__((ext_vector_type(8)));

#if __has_builtin(__builtin_amdgcn_fdot2)
#define FDOT2(a, b, c) __builtin_amdgcn_fdot2((a), (b), (c), false)
#else
#define FDOT2(a, b, c) fmaf((float)(a)[0], (float)(b)[0], fmaf((float)(a)[1], (float)(b)[1], (c)))
#endif

#if __has_builtin(__builtin_amdgcn_exp2f)
#define EXP2(x) __builtin_amdgcn_exp2f(x)
#else
#define EXP2(x) exp2f(x)
#endif
#if __has_builtin(__builtin_amdgcn_logf)
#define LOG2(x) __builtin_amdgcn_logf(x)
#else
#define LOG2(x) __log2f(x)
#endif

#define AS1 __attribute__((address_space(1)))
#define AS3 __attribute__((address_space(3)))

// LDS-drain barrier only (DMA ring stays in flight; counted vmcnt elsewhere)
#define BAR() do { asm volatile("s_waitcnt lgkmcnt(0)" ::: "memory"); __builtin_amdgcn_s_barrier(); } while (0)

// exact x * 2^n (n in [-126,127])
__device__ __forceinline__ float mul2n(float x, int n) {
    return x * __builtin_bit_cast(float, (n + 127) << 23);
}

template<int CTRL, int RM>
__device__ __forceinline__ float dppmax(float x) {
    int xi = __builtin_bit_cast(int, x);
    int yi = __builtin_amdgcn_update_dpp(xi, xi, CTRL, RM, 0xf, false);
    return fmaxf(x, __builtin_bit_cast(float, yi));
}
__device__ __forceinline__ float wave_max64(float x) {
    x = dppmax<0x111, 0xf>(x);  // row_shr:1
    x = dppmax<0x112, 0xf>(x);  // row_shr:2
    x = dppmax<0x114, 0xf>(x);  // row_shr:4
    x = dppmax<0x118, 0xf>(x);  // row_shr:8
    x = dppmax<0x142, 0xa>(x);  // row_bcast:15
    x = dppmax<0x143, 0xc>(x);  // row_bcast:31
    return __builtin_bit_cast(float, __builtin_amdgcn_readlane(__builtin_bit_cast(int, x), 63));
}

__global__ __launch_bounds__(NTH, 1) void crf_fwd(
    const float* __restrict__ feats,
    const int*   __restrict__ tags,
    const int*   __restrict__ mask,
    const float* __restrict__ start_t,
    const float* __restrict__ end_t,
    const float* __restrict__ trans,
    float*       __restrict__ out)
{
    const int b    = blockIdx.x;
    const int j    = threadIdx.x;     // owned OUTPUT column 0..255
    const int lane = j & 63;
    const int w    = j >> 6;          // wave 0..3 (owns cols [64w,64w+64))

    __shared__ __attribute__((aligned(16))) _Float16 qbuf[2][T];  // packed state, ping-pong (1 KB)
    __shared__ float ftile[8][T];                                 // feats DMA ring (8 KB)
    __shared__ int   msk[S];
    __shared__ __attribute__((aligned(16))) float redq[2][4];     // per-wave q max, ping-pong
    __shared__ float redF[4], redS[4], redg[4], redm[4], redi[4];

    // ---- prime DMA ring with feats tiles t=1..3
    #pragma unroll
    for (int tn = 1; tn <= 3; ++tn) {
        const float* src = feats + ((size_t)tn * B + b) * T + j;
        __builtin_amdgcn_global_load_lds((const AS1 void*)src,
                                         (AS3 void*)&ftile[tn][j], 4, 0, 0);
    }

    // ---- small per-thread loads
    const float endj = end_t[j];
    const float sc0  = start_t[j] + feats[(size_t)b * T + j];   // score at t=0
    msk[j]     = mask[j * B + b];
    msk[j + T] = mask[(j + T) * B + b];

    // ---- gold-score terms: two time steps per thread
    float gterm = 0.f, mcnt = 0.f;
    #pragma unroll
    for (int c = 0; c < 2; ++c) {
        const int t  = j + c * T;
        const int tg = tags[t * B + b];
        const int m  = mask[t * B + b];
        const float emit = feats[((size_t)t * B + b) * T + tg];
        mcnt += (float)m;
        if (t == 0) gterm += start_t[tg] + emit;
        else        gterm += m ? (emit + trans[tags[(t - 1) * B + b] * T + tg]) : 0.f;
    }
    #pragma unroll
    for (int o = 32; o > 0; o >>= 1) {
        gterm += __shfl_down(gterm, o, 64);
        mcnt  += __shfl_down(mcnt, o, 64);
    }
    if (lane == 0) { redg[w] = gterm; redm[w] = mcnt; }

    // ---- E column in registers: E2[p] = (exp(trans[2p][j]), exp(trans[2p+1][j])) fp16 (RTN)
    h2 E2[128];
    {
        const float* tc = trans + j;
        #pragma unroll
        for (int p = 0; p < 128; ++p) {
            const float e0 = EXP2(LOG2E * tc[(size_t)(2 * p) * T]);
            const float e1 = EXP2(LOG2E * tc[(size_t)(2 * p + 1) * T]);
            h2 v; v[0] = (_Float16)e0; v[1] = (_Float16)e1;
            E2[p] = v;
        }
    }

    // ---- init global exponent A from block max of sc0
    {
        const float mx = wave_max64(sc0);
        if (lane == 0) redi[w] = mx;
    }
    __syncthreads();   // full drain once (init; primed tiles also landed)

    float gold = 0.f;
    if (j == 0) {
        const float g  = redg[0] + redg[1] + redg[2] + redg[3];
        const float mc = redm[0] + redm[1] + redm[2] + redm[3];
        gold = g + end_t[tags[((int)mc - 1) * B + b]];
    }

    const float gmax0 = fmaxf(fmaxf(redi[0], redi[1]), fmaxf(redi[2], redi[3]));
    int A = (int)ceilf(gmax0 * LOG2E) + 10;
    float q = EXP2(fmaf(sc0, LOG2E, (float)(-A)));   // max(q) ~= 2^-10
    qbuf[0][j] = (_Float16)q;                        // RTN pack
    {
        const float mq = wave_max64(q);
        if (lane == 0) redq[0][w] = mq;
    }
    __syncthreads();   // qbuf[0]/redq[0] visible

    for (int t = 1; t < S; ++t) {
        const int cur = (t - 1) & 1;
        // ---- DMA prefetch t+3 (8-slot ring), counted wait: tile t landed
        if (t < S - 3) {
            const float* src = feats + ((size_t)(t + 3) * B + b) * T + j;
            __builtin_amdgcn_global_load_lds((const AS1 void*)src,
                                             (AS3 void*)&ftile[(t + 3) & 7][j], 4, 0, 0);
            asm volatile("s_waitcnt vmcnt(3)" ::: "memory");
        } else {
            asm volatile("s_waitcnt vmcnt(0)" ::: "memory");
        }

        // ---- step scale: k from previous q's block max; F = exp(ft)*2^-k (off GEMV path)
        const float ft = ftile[t & 7][j];
        const float4 rq = *(const float4*)&redq[cur][0];
        const int  mskt = msk[t];
        const float gm = fmaxf(fmaxf(rq.x, rq.y), fmaxf(rq.z, rq.w));
        const int  k  = ((__builtin_bit_cast(int, gm) >> 23) & 0xff) - 117;  // floor(log2 gm)+10
        const float F = EXP2(fmaf(ft, LOG2E, (float)(-k)));

        // ---- GEMV for own column: 32 uniform-broadcast b128 reads + 128 dot2, 4 acc chains
        const h8* qp = (const h8*)qbuf[cur];
        float a0 = 0.f, a1 = 0.f, a2 = 0.f, a3 = 0.f;
        #pragma unroll
        for (int r = 0; r < 32; ++r) {
            const h8 qv = qp[r];                       // same addr all lanes: broadcast
            a0 = FDOT2(E2[4 * r + 0], __builtin_shufflevector(qv, qv, 0, 1), a0);
            a1 = FDOT2(E2[4 * r + 1], __builtin_shufflevector(qv, qv, 2, 3), a1);
            a2 = FDOT2(E2[4 * r + 2], __builtin_shufflevector(qv, qv, 4, 5), a2);
            a3 = FDOT2(E2[4 * r + 3], __builtin_shufflevector(qv, qv, 6, 7), a3);
        }
        const float s  = (a0 + a1) + (a2 + a3);
        const float qn = s * F;
        const float qf = mul2n(q, -k);                 // frozen path (mask=0)
        q = mskt ? qn : qf;
        A += k;
        qbuf[t & 1][j] = (_Float16)q;                  // RTN pack, ping-pong
        {
            const float mq = wave_max64(q);            // for next step's k
            if (lane == 0) redq[t & 1][w] = mq;
        }
        BAR();   // the only barrier per step
    }

    // ---- finalize: score_j = (log2 q + A)*ln2; forward = LSE(score + end)
    const float u2 = LOG2(q) + (float)A + endj * LOG2E;
    {
        const float mw = wave_max64(u2);
        if (lane == 0) redF[w] = mw;
    }
    BAR();
    {
        const float gmax = fmaxf(fmaxf(redF[0], redF[1]), fmaxf(redF[2], redF[3]));
        float e = EXP2(u2 - gmax);
        #pragma unroll
        for (int o = 32; o > 0; o >>= 1) e += __shfl_xor(e, o, 64);
        if (lane == 0) redS[w] = e;
        BAR();
        if (j == 0) {
            const float ssum = redS[0] + redS[1] + redS[2] + redS[3];
            out[b] = (gmax + LOG2(ssum)) * LN2 - gold;
        }
    }
}

extern "C" void kernel_launch(void* const* d_in, const int* in_sizes, int n_in,
                              void* d_out, int out_size, void* d_ws, size_t ws_size,
                              hipStream_t stream) {
    const float* feats  = (const float*)d_in[0];
    const int*   tags   = (const int*)d_in[1];
    const int*   mask   = (const int*)d_in[2];
    const float* startt = (const float*)d_in[3];
    const float* endt   = (const float*)d_in[4];
    const float* transt = (const float*)d_in[5];
    float* out = (float*)d_out;
    crf_fwd<<<dim3(B), dim3(NTH), 0, stream>>>(feats, tags, mask, startt, endt, transt, out);
}

// Round 9
// 418.806 us; speedup vs baseline: 1.3155x; 1.3155x over previous
//
#include <hip/hip_runtime.h>
#include <math.h>

#define S 512
#define B 128
#define T 256
#define NB 16          // batches per block
#define NTH 256
#define FR 260         // padded ftile row stride (floats): +16B keeps alignment, breaks bank conflicts
#define LOG2E 1.44269504f
#define LN2 0.69314718f

typedef __fp16 h2 __attribute__((ext_vector_type(2)));
typedef __fp16 h8 __attribute__((ext_vector_type(8)));
typedef float f32x4 __attribute__((ext_vector_type(4)));

#if __has_builtin(__builtin_amdgcn_exp2f)
#define EXP2(x) __builtin_amdgcn_exp2f(x)
#else
#define EXP2(x) exp2f(x)
#endif
#if __has_builtin(__builtin_amdgcn_logf)
#define LOG2F(x) __builtin_amdgcn_logf(x)
#else
#define LOG2F(x) __log2f(x)
#endif

#define AS1 __attribute__((address_space(1)))
#define AS3 __attribute__((address_space(3)))
// LDS-drain barrier only (DMA ring stays in flight; counted vmcnt separately)
#define BAR() do { asm volatile("s_waitcnt lgkmcnt(0)" ::: "memory"); __builtin_amdgcn_s_barrier(); } while (0)

// exact x * 2^n (n in [-126,127])
__device__ __forceinline__ float mul2n(float x, int n) {
    return x * __builtin_bit_cast(float, (n + 127) << 23);
}

__global__ __launch_bounds__(NTH, 1) void crf_fwd(
    const float* __restrict__ feats,
    const int*   __restrict__ tags,
    const int*   __restrict__ mask,
    const float* __restrict__ start_t,
    const float* __restrict__ end_t,
    const float* __restrict__ trans,
    float*       __restrict__ out)
{
    const int tid = threadIdx.x;
    const int l   = tid & 63;
    const int w   = tid >> 6;     // wave 0..3: owns output states [64w, 64w+64)
    const int m   = l & 15;       // this thread's batch (M/N lane mapping)
    const int grp = l >> 4;       // 0..3
    const int b0  = blockIdx.x * NB;

    // qfrag: Q packed EXACTLY in MFMA B-fragment order: [kt][lane'][i] -> Q[m=lane'&15][k=kt*32+(lane'>>4)*8+i]
    __shared__ __attribute__((aligned(16))) __fp16 qfrag[2][8][64][8];     // 16 KB
    __shared__ __attribute__((aligned(16))) float ftile[4][NB][FR];        // 65 KB DMA ring
    __shared__ int msk16[S];
    __shared__ __attribute__((aligned(16))) float redq[2][NB][4];
    __shared__ __attribute__((aligned(16))) float redi[NB][4];
    __shared__ __attribute__((aligned(16))) float redF[NB][4];
    __shared__ __attribute__((aligned(16))) float redS[NB][4];
    __shared__ float redg[NB][16], redm[NB][16];
    __shared__ float goldv[NB];
    __shared__ __attribute__((aligned(16))) float endf[T];

    // ---- prime DMA ring: feats tiles t=1..3, one full row m per instruction (dst = base + lane*16)
    #pragma unroll
    for (int tn = 1; tn <= 3; ++tn) {
        #pragma unroll
        for (int q = 0; q < 4; ++q) {
            const int mr = 4 * q + w;
            const float* src = feats + ((size_t)tn * B + b0 + mr) * T + l * 4;
            __builtin_amdgcn_global_load_lds((const AS1 void*)src,
                                             (AS3 void*)&ftile[tn & 3][mr][l * 4], 16, 0, 0);
        }
    }

    if (tid < T) endf[tid] = end_t[tid];

    // ---- mask bits: msk16[t] bit m = mask[t][b0+m]
    #pragma unroll
    for (int c = 0; c < 2; ++c) {
        const int t = tid + 256 * c;
        const int4 ma = *(const int4*)&mask[(size_t)t * B + b0];
        const int4 mb = *(const int4*)&mask[(size_t)t * B + b0 + 4];
        const int4 mcq = *(const int4*)&mask[(size_t)t * B + b0 + 8];
        const int4 md = *(const int4*)&mask[(size_t)t * B + b0 + 12];
        const int bits = (ma.x & 1) | ((ma.y & 1) << 1) | ((ma.z & 1) << 2) | ((ma.w & 1) << 3)
                       | ((mb.x & 1) << 4) | ((mb.y & 1) << 5) | ((mb.z & 1) << 6) | ((mb.w & 1) << 7)
                       | ((mcq.x & 1) << 8) | ((mcq.y & 1) << 9) | ((mcq.z & 1) << 10) | ((mcq.w & 1) << 11)
                       | ((md.x & 1) << 12) | ((md.y & 1) << 13) | ((md.z & 1) << 14) | ((md.w & 1) << 15);
        msk16[t] = bits;
    }

    // ---- score at t=0 for this thread's 16 (batch m, state j) cells
    float sc0v[4][4];
    #pragma unroll
    for (int mt = 0; mt < 4; ++mt) {
        const int j0 = 64 * w + 16 * mt + 4 * grp;
        const float4 f0 = *(const float4*)&feats[((size_t)b0 + m) * T + j0];
        const float4 st = *(const float4*)&start_t[j0];
        sc0v[mt][0] = st.x + f0.x; sc0v[mt][1] = st.y + f0.y;
        sc0v[mt][2] = st.z + f0.z; sc0v[mt][3] = st.w + f0.w;
    }

    // ---- gold-score partials: thread (batch tid&15, chunk tid>>4) covers 32 time steps
    {
        const int mg = tid & 15, chunk = tid >> 4;
        const int t0 = chunk * 32;
        float g = 0.f, mc = 0.f;
        int tgp = (t0 > 0) ? tags[(size_t)(t0 - 1) * B + b0 + mg] : 0;
        #pragma unroll
        for (int tt = 0; tt < 32; ++tt) {
            const int t = t0 + tt;
            const int tg = tags[(size_t)t * B + b0 + mg];
            const int mk = mask[(size_t)t * B + b0 + mg];
            const float emit = feats[((size_t)t * B + b0 + mg) * T + tg];
            mc += (float)mk;
            if (t == 0) g += start_t[tg] + emit;
            else        g += mk ? (emit + trans[(size_t)tgp * T + tg]) : 0.f;
            tgp = tg;
        }
        redg[mg][chunk] = g;
        redm[mg][chunk] = mc;
    }

    // ---- E^T fragments in registers (A operand): A[row=l&15][k=kt*32+grp*8+i] = exp(trans[k][j])
    h8 E[4][8];
    #pragma unroll
    for (int mt = 0; mt < 4; ++mt) {
        const int j = 64 * w + 16 * mt + m;
        #pragma unroll
        for (int kt = 0; kt < 8; ++kt) {
            const int kb = kt * 32 + grp * 8;
            h8 v;
            #pragma unroll
            for (int i = 0; i < 8; ++i)
                v[i] = (__fp16)EXP2(LOG2E * trans[(size_t)(kb + i) * T + j]);
            E[mt][kt] = v;
        }
    }

    // ---- per-batch max of sc0 (wave level)
    {
        float lm = sc0v[0][0];
        #pragma unroll
        for (int mt = 0; mt < 4; ++mt)
            #pragma unroll
            for (int p = 0; p < 4; ++p) lm = fmaxf(lm, sc0v[mt][p]);
        lm = fmaxf(lm, __shfl_xor(lm, 16, 64));
        lm = fmaxf(lm, __shfl_xor(lm, 32, 64));
        if (grp == 0) redi[m][w] = lm;
    }

    __syncthreads();

    if (tid < NB) {
        float g = 0.f, mc = 0.f;
        #pragma unroll
        for (int c = 0; c < 16; ++c) { g += redg[tid][c]; mc += redm[tid][c]; }
        const int se = (int)mc - 1;
        goldv[tid] = g + end_t[tags[(size_t)se * B + b0 + tid]];
    }

    // ---- linear-state init: q = 2^(sc0*log2e - A_m), per-batch A_m so max ~= 2^-10
    const float4 ri = *(const float4*)&redi[m][0];
    const float gmax0 = fmaxf(fmaxf(ri.x, ri.y), fmaxf(ri.z, ri.w));
    int A = (int)ceilf(gmax0 * LOG2E) + 10;

    float qv[4][4];
    {
        float lmax = 0.f;
        #pragma unroll
        for (int mt = 0; mt < 4; ++mt)
            #pragma unroll
            for (int p = 0; p < 4; ++p) {
                const float x = EXP2(fmaf(sc0v[mt][p], LOG2E, (float)(-A)));
                qv[mt][p] = x;
                lmax = fmaxf(lmax, x);
            }
        #pragma unroll
        for (int mt = 0; mt < 4; ++mt) {
            const int ktw = 2 * w + (mt >> 1);
            const int lp  = (((2 * mt + (grp >> 1)) & 3) << 4) | m;
            const int i0  = 4 * (grp & 1);
            int2 wv;
            wv.x = __builtin_bit_cast(int, (h2)__builtin_amdgcn_cvt_pkrtz(qv[mt][0], qv[mt][1]));
            wv.y = __builtin_bit_cast(int, (h2)__builtin_amdgcn_cvt_pkrtz(qv[mt][2], qv[mt][3]));
            *(int2*)&qfrag[0][ktw][lp][i0] = wv;
        }
        lmax = fmaxf(lmax, __shfl_xor(lmax, 16, 64));
        lmax = fmaxf(lmax, __shfl_xor(lmax, 32, 64));
        if (grp == 0) redq[0][m][w] = lmax;
    }

    // ---- main recursion: one MFMA step advances all 16 batches
    for (int t = 1; t < S; ++t) {
        const int cur = (t - 1) & 1, nxt = t & 1;
        if (t <= 509) asm volatile("s_waitcnt vmcnt(8)" ::: "memory");  // own rows of tile t landed
        else          asm volatile("s_waitcnt vmcnt(0)" ::: "memory");
        BAR();   // the only barrier per step: qfrag[cur]/redq[cur]/ftile[t] now visible

        const int mbits = msk16[t];
        const float4 rq = *(const float4*)&redq[cur][m][0];
        h8 bf[8];
        #pragma unroll
        for (int kt = 0; kt < 8; ++kt)
            bf[kt] = *(const h8*)&qfrag[cur][kt][l][0];   // conflict-free: contiguous lane*16

        float4 ftv[4]; int2 qo[4];
        #pragma unroll
        for (int mt = 0; mt < 4; ++mt) {
            const int j0 = 64 * w + 16 * mt + 4 * grp;
            ftv[mt] = *(const float4*)&ftile[t & 3][m][j0];
            const int ktw = 2 * w + (mt >> 1);
            const int lp  = (((2 * mt + (grp >> 1)) & 3) << 4) | m;
            const int i0  = 4 * (grp & 1);
            qo[mt] = *(const int2*)&qfrag[cur][ktw][lp][i0];   // frozen-path old q
        }

        if (t + 3 < S) {
            #pragma unroll
            for (int q = 0; q < 4; ++q) {
                const int mr = 4 * q + w;
                const float* src = feats + ((size_t)(t + 3) * B + b0 + mr) * T + l * 4;
                __builtin_amdgcn_global_load_lds((const AS1 void*)src,
                                                 (AS3 void*)&ftile[(t + 3) & 3][mr][l * 4], 16, 0, 0);
            }
        }

        // D[j][m] = sum_k E^T[j][k] * Q[m][k] — K-permutation-invariant (A/B share the k-map)
        f32x4 acc0 = {0.f, 0.f, 0.f, 0.f}, acc1 = acc0, acc2 = acc0, acc3 = acc0;
        #pragma unroll
        for (int kt = 0; kt < 8; ++kt) {
            acc0 = __builtin_amdgcn_mfma_f32_16x16x32_f16(E[0][kt], bf[kt], acc0, 0, 0, 0);
            acc1 = __builtin_amdgcn_mfma_f32_16x16x32_f16(E[1][kt], bf[kt], acc1, 0, 0, 0);
            acc2 = __builtin_amdgcn_mfma_f32_16x16x32_f16(E[2][kt], bf[kt], acc2, 0, 0, 0);
            acc3 = __builtin_amdgcn_mfma_f32_16x16x32_f16(E[3][kt], bf[kt], acc3, 0, 0, 0);
        }

        // elementwise: q' = D * exp(ft) * 2^-k_m  (k_m from previous step's per-batch max)
        const float gm = fmaxf(fmaxf(rq.x, rq.y), fmaxf(rq.z, rq.w));
        const int k = ((__builtin_bit_cast(int, gm) >> 23) & 0xff) - 117;  // floor(log2 gm)+10
        const int mskb = (mbits >> m) & 1;
        const float negk = (float)(-k);
        float lmax = 0.f;
        #pragma unroll
        for (int mt = 0; mt < 4; ++mt) {
            const f32x4 ac = (mt == 0) ? acc0 : (mt == 1) ? acc1 : (mt == 2) ? acc2 : acc3;
            const h2 q01 = __builtin_bit_cast(h2, qo[mt].x);
            const h2 q23 = __builtin_bit_cast(h2, qo[mt].y);
            const float qold[4] = {(float)q01[0], (float)q01[1], (float)q23[0], (float)q23[1]};
            const float fts[4] = {ftv[mt].x, ftv[mt].y, ftv[mt].z, ftv[mt].w};
            #pragma unroll
            for (int p = 0; p < 4; ++p) {
                const float F = EXP2(fmaf(fts[p], LOG2E, negk));
                const float qn = ac[p] * F;
                const float qf = mul2n(qold[p], -k);   // frozen path (mask=0), exact
                const float x = mskb ? qn : qf;
                qv[mt][p] = x;
                lmax = fmaxf(lmax, x);
            }
        }
        A += k;

        // pack q' back into B-fragment order (b64 writes, 2-way banks) + per-batch max
        #pragma unroll
        for (int mt = 0; mt < 4; ++mt) {
            const int ktw = 2 * w + (mt >> 1);
            const int lp  = (((2 * mt + (grp >> 1)) & 3) << 4) | m;
            const int i0  = 4 * (grp & 1);
            int2 wv;
            wv.x = __builtin_bit_cast(int, (h2)__builtin_amdgcn_cvt_pkrtz(qv[mt][0], qv[mt][1]));
            wv.y = __builtin_bit_cast(int, (h2)__builtin_amdgcn_cvt_pkrtz(qv[mt][2], qv[mt][3]));
            *(int2*)&qfrag[nxt][ktw][lp][i0] = wv;
        }
        lmax = fmaxf(lmax, __shfl_xor(lmax, 16, 64));
        lmax = fmaxf(lmax, __shfl_xor(lmax, 32, 64));
        if (grp == 0) redq[nxt][m][w] = lmax;
    }

    // ---- finalize: score = (log2 q + A_m)*ln2; forward_m = LSE_j(score + end)
    float u[4][4];
    float lmax2 = -3.0e38f;
    #pragma unroll
    for (int mt = 0; mt < 4; ++mt) {
        const int j0 = 64 * w + 16 * mt + 4 * grp;
        const float4 ev = *(const float4*)&endf[j0];
        const float es[4] = {ev.x, ev.y, ev.z, ev.w};
        #pragma unroll
        for (int p = 0; p < 4; ++p) {
            const float uu = LOG2F(qv[mt][p]) + (float)A + es[p] * LOG2E;
            u[mt][p] = uu;
            lmax2 = fmaxf(lmax2, uu);
        }
    }
    lmax2 = fmaxf(lmax2, __shfl_xor(lmax2, 16, 64));
    lmax2 = fmaxf(lmax2, __shfl_xor(lmax2, 32, 64));
    if (grp == 0) redF[m][w] = lmax2;
    BAR();
    {
        const float4 rf = *(const float4*)&redF[m][0];
        const float M = fmaxf(fmaxf(rf.x, rf.y), fmaxf(rf.z, rf.w));
        float se = 0.f;
        #pragma unroll
        for (int mt = 0; mt < 4; ++mt)
            #pragma unroll
            for (int p = 0; p < 4; ++p) se += EXP2(u[mt][p] - M);
        se += __shfl_xor(se, 16, 64);
        se += __shfl_xor(se, 32, 64);
        if (grp == 0) redS[m][w] = se;
    }
    BAR();
    if (tid < NB) {
        const float4 rf = *(const float4*)&redF[tid][0];
        const float4 rs = *(const float4*)&redS[tid][0];
        const float M = fmaxf(fmaxf(rf.x, rf.y), fmaxf(rf.z, rf.w));
        out[b0 + tid] = (M + LOG2F(rs.x + rs.y + rs.z + rs.w)) * LN2 - goldv[tid];
    }
}

extern "C" void kernel_launch(void* const* d_in, const int* in_sizes, int n_in,
                              void* d_out, int out_size, void* d_ws, size_t ws_size,
                              hipStream_t stream) {
    const float* feats  = (const float*)d_in[0];
    const int*   tags   = (const int*)d_in[1];
    const int*   mask   = (const int*)d_in[2];
    const float* startt = (const float*)d_in[3];
    const float* endt   = (const float*)d_in[4];
    const float* transt = (const float*)d_in[5];
    float* out = (float*)d_out;
    crf_fwd<<<dim3(B / NB), dim3(NTH), 0, stream>>>(feats, tags, mask, startt, endt, transt, out);
}